// Round 1
// baseline (250.918 us; speedup 1.0000x reference)
//
#include <hip/hip_runtime.h>

#define HW 4096
#define NCH 256
#define DIM 128
#define NPROTO 512

typedef __attribute__((ext_vector_type(4))) float f32x4;
typedef __attribute__((ext_vector_type(8))) short s16x8;

__device__ __forceinline__ unsigned short f2bf(float f) {
  union { float f; unsigned u; } v; v.f = f;
  unsigned r = v.u + 0x7fffu + ((v.u >> 16) & 1u);
  return (unsigned short)(r >> 16);
}

// async global->LDS, 16B per lane; LDS dest = wave-uniform base + lane*16
__device__ __forceinline__ void gload_lds16(const void* g, void* l) {
  __builtin_amdgcn_global_load_lds(
      (const __attribute__((address_space(1))) void*)g,
      (__attribute__((address_space(3))) void*)l, 16, 0, 0);
}

// ---------------------------------------------------------------------------
// prep: P -> bf16 row-major [512][128] + pn2[512]; W -> bf16 row-major [128][256]
// (attn reads P/q fragments straight from global now; proj stages W via
//  global_load_lds, so plain row-major layouts suffice)
// ---------------------------------------------------------------------------
__global__ __launch_bounds__(256) void prep_kernel(const float* __restrict__ P,
                                                   const float* __restrict__ Wm,
                                                   unsigned short* __restrict__ Pbf,
                                                   unsigned short* __restrict__ Wbf,
                                                   float* __restrict__ pn2) {
  const int tid = threadIdx.x;
  const int b = blockIdx.x;
  if (b < 8) {
    const int n  = b * 64 + (tid >> 2);
    const int qt = tid & 3;
    const float* row = P + n * DIM + qt * 32;
    unsigned short* dst = Pbf + (size_t)n * DIM + qt * 32;
    float ssq = 0.f;
#pragma unroll
    for (int u = 0; u < 8; ++u) {
      f32x4 v = *(const f32x4*)(row + 4 * u);
      ssq += v.x * v.x + v.y * v.y + v.z * v.z + v.w * v.w;
      dst[4 * u + 0] = f2bf(v.x);
      dst[4 * u + 1] = f2bf(v.y);
      dst[4 * u + 2] = f2bf(v.z);
      dst[4 * u + 3] = f2bf(v.w);
    }
    ssq += __shfl_xor(ssq, 1);
    ssq += __shfl_xor(ssq, 2);
    if (qt == 0) pn2[n] = ssq;
  } else {
    const int idx = ((b - 8) * 256 + tid) * 16;  // 8 blocks * 256 thr * 16 = 32768
#pragma unroll
    for (int u = 0; u < 4; ++u) {
      f32x4 v = *(const f32x4*)(Wm + idx + 4 * u);
      unsigned short* d = Wbf + idx + 4 * u;
      d[0] = f2bf(v.x); d[1] = f2bf(v.y); d[2] = f2bf(v.z); d[3] = f2bf(v.w);
    }
  }
}

// ---------------------------------------------------------------------------
// proj: q[t][d] = sum_c x * W + b, bf16 out [65536][128].
// W staged via global_load_lds (zero VALU): LDS linear [128][64] shorts,
// XOR-swizzled SOURCE addresses + XOR-swizzled ds_read (row stride is 128B,
// so unswizzled b128 reads would all hit one bank group).
// ---------------------------------------------------------------------------
__global__ __launch_bounds__(512) void proj_kernel(const float* __restrict__ x,
                                                   const unsigned short* __restrict__ Wbf,
                                                   const float* __restrict__ bias,
                                                   unsigned short* __restrict__ qbf) {
  __shared__ __align__(16) unsigned short x_s[128 * 72];  // [pix][c] pad 64->72
  __shared__ __align__(16) unsigned short w_s[128 * 64];  // [d][c] linear, swizzled
  const int tid  = threadIdx.x;
  const int p0   = blockIdx.x * 128;
  const int nimg = p0 >> 12;
  const int hw0  = p0 & 4095;
  const float* xbase = x + (size_t)nimg * NCH * HW + hw0;
  const int wave = tid >> 6, lane = tid & 63;
  const int l15 = lane & 15, l4 = lane >> 4;

  f32x4 acc[8];
#pragma unroll
  for (int j = 0; j < 8; ++j)
#pragma unroll
    for (int r = 0; r < 4; ++r) acc[j][r] = 0.f;

  const int wrow0 = 8 * wave + (lane >> 3);  // W staging: 8 rows/wave/round
  const int wc8   = lane & 7;                // 16B unit within 128B row

  for (int c0 = 0; c0 < NCH; c0 += 64) {
    // W: async, swizzled source -> linear LDS
#pragma unroll
    for (int t = 0; t < 2; ++t) {
      const int row = 64 * t + wrow0;
      const unsigned short* src =
          Wbf + (size_t)row * NCH + c0 + ((wc8 ^ (row & 7)) << 3);
      gload_lds16(src, (char*)w_s + t * 8192 + wave * 1024);
    }
    // x: f32 -> bf16 transpose into [pix][c]
    {
      const int f = tid & 31, cl = tid >> 5;
#pragma unroll
      for (int r = 0; r < 4; ++r) {
        const int cc = cl + 16 * r;
        f32x4 v = *(const f32x4*)(xbase + (size_t)(c0 + cc) * HW + 4 * f);
        x_s[(4 * f + 0) * 72 + cc] = f2bf(v.x);
        x_s[(4 * f + 1) * 72 + cc] = f2bf(v.y);
        x_s[(4 * f + 2) * 72 + cc] = f2bf(v.z);
        x_s[(4 * f + 3) * 72 + cc] = f2bf(v.w);
      }
    }
    __syncthreads();  // compiler drains vmcnt before barrier -> W ready
#pragma unroll
    for (int kc = 0; kc < 64; kc += 32) {
      s16x8 a = *(const s16x8*)&x_s[(16 * wave + l15) * 72 + kc + 8 * l4];
      const int ub = (kc >> 3) + l4;  // 16B unit index 0..7
#pragma unroll
      for (int j = 0; j < 8; ++j) {
        s16x8 b = *(const s16x8*)&w_s[(16 * j + l15) * 64 + ((ub ^ (l15 & 7)) << 3)];
        acc[j] = __builtin_amdgcn_mfma_f32_16x16x32_bf16(a, b, acc[j], 0, 0, 0);
      }
    }
    __syncthreads();
  }
  // epilogue: C/D layout col=lane&15 (=d), row=(lane>>4)*4+reg (=pix)
  const int mb = 16 * wave + 4 * l4;
#pragma unroll
  for (int j = 0; j < 8; ++j) {
    const int d = 16 * j + l15;
    const float bv = bias[d];
#pragma unroll
    for (int r = 0; r < 4; ++r)
      qbf[(size_t)(p0 + mb + r) * DIM + d] = f2bf(acc[j][r] + bv);
  }
}

// ---------------------------------------------------------------------------
// attn: 256 thr (4 waves), 32 pixels x 512 protos per block, 2048 blocks.
// Wave wv owns protos [128wv, 128wv+128). A/B fragments read DIRECTLY from
// global (q tile 8KB, P 128KB -- both L2-resident; LDS staging was overhead).
// Softmax in exp2 domain; direct f32x4 stores from acc (r = consecutive
// pixels), no LDS transpose, no bf16 roundtrip on the output.
// ---------------------------------------------------------------------------
__global__ __launch_bounds__(256, 4) void attn_kernel(const unsigned short* __restrict__ qbf,
                                                      const unsigned short* __restrict__ Pbf,
                                                      const float* __restrict__ pn2,
                                                      const float* __restrict__ gptr,
                                                      float* __restrict__ out) {
  __shared__ float red[4 * 32];
  __shared__ float rmx[32];
  __shared__ float rinv[32];

  const int tid  = threadIdx.x;
  const int p0   = blockIdx.x * 32;
  const int nimg = p0 >> 12;
  const int hw0  = p0 & 4095;
  const int wv = tid >> 6, lane = tid & 63;
  const int l15 = lane & 15, l4 = lane >> 4;

  const float g2  = fabsf(gptr[0]) * 1.44269504088896340736f;  // |gamma| * log2(e)
  const float tg2 = 2.f * g2;

  f32x4 acc[2][8];
#pragma unroll
  for (int i = 0; i < 2; ++i)
#pragma unroll
    for (int j = 0; j < 8; ++j)
#pragma unroll
      for (int r = 0; r < 4; ++r) acc[i][j][r] = 0.f;

  const unsigned short* qrow = qbf + (size_t)(p0 + l15) * DIM + 8 * l4;
  const unsigned short* prow = Pbf + (size_t)(128 * wv + l15) * DIM + 8 * l4;

#pragma unroll
  for (int ch = 0; ch < 4; ++ch) {
    const int dk = 32 * ch;
    s16x8 afr[2];
#pragma unroll
    for (int i = 0; i < 2; ++i)
      afr[i] = *(const s16x8*)(qrow + (size_t)(16 * i) * DIM + dk);
#pragma unroll
    for (int j = 0; j < 8; ++j) {
      s16x8 bfr = *(const s16x8*)(prow + (size_t)(16 * j) * DIM + dk);
#pragma unroll
      for (int i = 0; i < 2; ++i)
        acc[i][j] = __builtin_amdgcn_mfma_f32_16x16x32_bf16(afr[i], bfr, acc[i][j], 0, 0, 0);
    }
  }

  float cj[8];
#pragma unroll
  for (int j = 0; j < 8; ++j) cj[j] = g2 * pn2[128 * wv + 16 * j + l15];

  const int rbase = 4 * l4;  // row within 16-tile = rbase + r; full row = 16i + rbase + r

  // logits (base-2) + row max. lane holds rows m=16i+4*l4+r, cols n=128wv+16j+l15
#pragma unroll
  for (int i = 0; i < 2; ++i)
#pragma unroll
    for (int r = 0; r < 4; ++r) {
      float m = -1e30f;
#pragma unroll
      for (int j = 0; j < 8; ++j) {
        float lv = fmaf(acc[i][j][r], tg2, -cj[j]);
        acc[i][j][r] = lv;
        m = fmaxf(m, lv);
      }
#pragma unroll
      for (int s = 1; s < 16; s <<= 1) m = fmaxf(m, __shfl_xor(m, s));
      if (l15 == 0) red[wv * 32 + 16 * i + rbase + r] = m;
    }
  __syncthreads();
  if (tid < 32) {
    float M = red[tid];
#pragma unroll
    for (int w = 1; w < 4; ++w) M = fmaxf(M, red[w * 32 + tid]);
    rmx[tid] = M;
  }
  __syncthreads();

  // exp2 + row sum
#pragma unroll
  for (int i = 0; i < 2; ++i)
#pragma unroll
    for (int r = 0; r < 4; ++r) {
      const float M = rmx[16 * i + rbase + r];
      float s = 0.f;
#pragma unroll
      for (int j = 0; j < 8; ++j) {
        float e = exp2f(acc[i][j][r] - M);
        acc[i][j][r] = e;
        s += e;
      }
#pragma unroll
      for (int t = 1; t < 16; t <<= 1) s += __shfl_xor(s, t);
      if (l15 == 0) red[wv * 32 + 16 * i + rbase + r] = s;
    }
  __syncthreads();
  if (tid < 32) {
    float S = red[tid] + red[32 + tid] + red[64 + tid] + red[96 + tid];
    rinv[tid] = 1.f / S;
  }
  __syncthreads();

  float inv[2][4];
#pragma unroll
  for (int i = 0; i < 2; ++i)
#pragma unroll
    for (int r = 0; r < 4; ++r) inv[i][r] = rinv[16 * i + rbase + r];

  // direct stores: f32x4 over r = 4 consecutive pixels within k-plane
  float* obase = out + (size_t)nimg * NPROTO * HW + hw0;
#pragma unroll
  for (int i = 0; i < 2; ++i) {
    const int px = 16 * i + rbase;
#pragma unroll
    for (int j = 0; j < 8; ++j) {
      const int k = 128 * wv + 16 * j + l15;
      f32x4 o = acc[i][j];
      o.x *= inv[i][0]; o.y *= inv[i][1]; o.z *= inv[i][2]; o.w *= inv[i][3];
      *(f32x4*)(obase + (size_t)k * HW + px) = o;
    }
  }
}

extern "C" void kernel_launch(void* const* d_in, const int* in_sizes, int n_in,
                              void* d_out, int out_size, void* d_ws, size_t ws_size,
                              hipStream_t stream) {
  const float* x     = (const float*)d_in[0];
  const float* Wm    = (const float*)d_in[1];
  const float* bias  = (const float*)d_in[2];
  const float* prot  = (const float*)d_in[3];
  const float* gamma = (const float*)d_in[4];
  float* out = (float*)d_out;

  // workspace: q bf16 (16 MiB) | P bf16 (128 KiB) | pn2 (2 KiB) | W bf16 (64 KiB)
  unsigned short* q_ws  = (unsigned short*)d_ws;
  unsigned short* P_ws  = (unsigned short*)((char*)d_ws + 16777216);
  float*          pn2_w = (float*)((char*)d_ws + 16777216 + 131072);
  unsigned short* W_ws  = (unsigned short*)((char*)d_ws + 16777216 + 131072 + 2048);

  prep_kernel<<<16, 256, 0, stream>>>(prot, Wm, P_ws, W_ws, pn2_w);
  proj_kernel<<<512, 512, 0, stream>>>(x, W_ws, bias, q_ws);
  attn_kernel<<<2048, 256, 0, stream>>>(q_ws, P_ws, pn2_w, gamma, out);
}

// Round 3
// 215.479 us; speedup vs baseline: 1.1645x; 1.1645x over previous
//
#include <hip/hip_runtime.h>

#define HW 4096
#define NCH 256
#define DIM 128
#define NPROTO 512

typedef __attribute__((ext_vector_type(4))) float f32x4;
typedef __attribute__((ext_vector_type(8))) short s16x8;

__device__ __forceinline__ unsigned short f2bf(float f) {
  union { float f; unsigned u; } v; v.f = f;
  unsigned r = v.u + 0x7fffu + ((v.u >> 16) & 1u);
  return (unsigned short)(r >> 16);
}

// async global->LDS, 16B/lane; LDS dest = wave-uniform base + lane*16
__device__ __forceinline__ void gload_lds16(const void* g, void* l) {
  __builtin_amdgcn_global_load_lds(
      (const __attribute__((address_space(1))) void*)g,
      (__attribute__((address_space(3))) void*)l, 16, 0, 0);
}

// ---------------------------------------------------------------------------
// prep: P -> bf16 chunked Pr[ch][512][32] (+pn2); W -> bf16 row-major [128][256]
// ---------------------------------------------------------------------------
__global__ __launch_bounds__(256) void prep_kernel(const float* __restrict__ P,
                                                   const float* __restrict__ Wm,
                                                   unsigned short* __restrict__ Pr,
                                                   unsigned short* __restrict__ Wbf,
                                                   float* __restrict__ pn2) {
  const int tid = threadIdx.x;
  const int b = blockIdx.x;
  if (b < 8) {
    const int n  = b * 64 + (tid >> 2);
    const int qt = tid & 3;  // d-chunk 32*qt..
    const float* row = P + n * DIM + qt * 32;
    unsigned short* dst = Pr + ((size_t)qt * NPROTO + n) * 32;
    float ssq = 0.f;
#pragma unroll
    for (int u = 0; u < 8; ++u) {
      f32x4 v = *(const f32x4*)(row + 4 * u);
      ssq += v.x * v.x + v.y * v.y + v.z * v.z + v.w * v.w;
      dst[4 * u + 0] = f2bf(v.x);
      dst[4 * u + 1] = f2bf(v.y);
      dst[4 * u + 2] = f2bf(v.z);
      dst[4 * u + 3] = f2bf(v.w);
    }
    ssq += __shfl_xor(ssq, 1);
    ssq += __shfl_xor(ssq, 2);
    if (qt == 0) pn2[n] = ssq;
  } else {
    const int idx = ((b - 8) * 256 + tid) * 16;  // 8*256*16 = 32768 = 128*256
#pragma unroll
    for (int u = 0; u < 4; ++u) {
      f32x4 v = *(const f32x4*)(Wm + idx + 4 * u);
      unsigned short* d = Wbf + idx + 4 * u;
      d[0] = f2bf(v.x); d[1] = f2bf(v.y); d[2] = f2bf(v.z); d[3] = f2bf(v.w);
    }
  }
}

// ---------------------------------------------------------------------------
// fused: per block 64 px x 512 protos, 512 thr (8 waves), 1024 blocks.
// Phase 1: q[64][128] = x W^T + b, K-step 64 channels (verified geometry).
//   x: channel-pair packed b32 writes, 16B-unit XOR swizzle keyed (row>>2)&7
//      (write banks: all 32, 2 lanes each = free; reads 16B-aligned b128).
//   W: global_load_lds width-16, source-XOR swizzle (verified round 1).
// Phase 1.5: q + bias -> bf16 q_s[64][136] (no HBM round-trip).
// Phase 2: proven attn: P chunks reg-prefetched (T14) into P_s[512][40],
//   exp2-domain softmax, direct f32x4 stores (r = 4 consecutive px).
// LDS: q_s 17408 | {x_s 9216 + w_s 16384} overlay P_s 40960 | red 2560.
// ---------------------------------------------------------------------------
__global__ __launch_bounds__(512, 4) void fused_kernel(
    const float* __restrict__ x, const unsigned short* __restrict__ Wbf,
    const float* __restrict__ bias, const unsigned short* __restrict__ Pr,
    const float* __restrict__ pn2, const float* __restrict__ gptr,
    float* __restrict__ out) {
  __shared__ __align__(16) char smem[61440];
  unsigned short* q_s = (unsigned short*)smem;                   // [64][136]
  char*           x_b = smem + 17408;                            // [64] rows, 144B stride
  unsigned short* w_s = (unsigned short*)(smem + 17408 + 9216);  // [128][64]
  unsigned short* P_s = (unsigned short*)(smem + 17408);         // [512][40]
  float* red  = (float*)(smem + 58880);                          // [8][64]
  float* rmx  = (float*)(smem + 60928);                          // [64]
  float* rinv = (float*)(smem + 61184);                          // [64]

  const int tid  = threadIdx.x;
  const int p0   = blockIdx.x * 64;
  const int nimg = p0 >> 12;
  const int hw0  = p0 & 4095;
  const int wave = tid >> 6, lane = tid & 63;
  const int l15 = lane & 15, l4 = lane >> 4;
  const int wr = wave >> 2, wc = wave & 3;  // phase-1 tile: px 32wr+, d 32wc+

  // ---------------- phase 1: q = x W^T ----------------
  f32x4 acc1[2][2];
#pragma unroll
  for (int i = 0; i < 2; ++i)
#pragma unroll
    for (int j = 0; j < 2; ++j)
#pragma unroll
      for (int r = 0; r < 4; ++r) acc1[i][j][r] = 0.f;

  const float* xb = x + (size_t)nimg * NCH * HW + hw0;
  const int f  = tid & 15;         // px quad: pixels 4f..4f+3
  const int cp = tid >> 4;         // channel pair 2cp,2cp+1 (0..31)
  const int wrow = 8 * wave + (lane >> 3);  // W staging row base
  const int wu   = lane & 7;                // 16B unit in 128B row

  for (int c0 = 0; c0 < NCH; c0 += 64) {
    // W: async, swizzled source -> linear LDS [128][64]
#pragma unroll
    for (int t = 0; t < 2; ++t) {
      const int row = 64 * t + wrow;
      const unsigned short* src =
          Wbf + (size_t)row * NCH + c0 + ((wu ^ (row & 7)) << 3);
      gload_lds16(src, (char*)w_s + t * 8192 + wave * 1024);
    }
    // x: 2 channel-rows at px quad f -> pair-packed b32 swizzled writes
    f32x4 v0 = *(const f32x4*)(xb + (size_t)(c0 + 2 * cp + 0) * HW + 4 * f);
    f32x4 v1 = *(const f32x4*)(xb + (size_t)(c0 + 2 * cp + 1) * HW + 4 * f);
#pragma unroll
    for (int s = 0; s < 4; ++s) {
      const int row = 4 * f + s;
      unsigned pk = (unsigned)f2bf(v0[s]) | ((unsigned)f2bf(v1[s]) << 16);
      *(unsigned*)(x_b + row * 144 + ((4 * cp) ^ (((row >> 2) & 7) << 4))) = pk;
    }
    __syncthreads();
#pragma unroll
    for (int kc = 0; kc < 64; kc += 32) {
      const int ub = (kc >> 3) + l4;  // 16B unit 0..7
      s16x8 a[2];
#pragma unroll
      for (int i = 0; i < 2; ++i) {
        const int row = 32 * wr + 16 * i + l15;
        a[i] = *(const s16x8*)(x_b + row * 144 + 16 * (ub ^ ((row >> 2) & 7)));
      }
#pragma unroll
      for (int j = 0; j < 2; ++j) {
        s16x8 b = *(const s16x8*)&w_s[(32 * wc + 16 * j + l15) * 64 +
                                      ((ub ^ (l15 & 7)) << 3)];
#pragma unroll
        for (int i = 0; i < 2; ++i)
          acc1[i][j] = __builtin_amdgcn_mfma_f32_16x16x32_bf16(a[i], b, acc1[i][j], 0, 0, 0);
      }
    }
    __syncthreads();
  }

  // ---------------- phase 1.5: q + bias -> q_s bf16 ----------------
  // C/D layout: col = l15 (d within 16-tile), row = 4*l4 + r (px)
#pragma unroll
  for (int j = 0; j < 2; ++j) {
    const int d = 32 * wc + 16 * j + l15;
    const float bv = bias[d];
#pragma unroll
    for (int i = 0; i < 2; ++i) {
      const int px = 32 * wr + 16 * i + 4 * l4;
#pragma unroll
      for (int r = 0; r < 4; ++r)
        q_s[(px + r) * 136 + d] = f2bf(acc1[i][j][r] + bv);
    }
  }

  // ---------------- phase 2: attn ----------------
  s16x8 pf[4];  // register prefetch of P chunk (T14)
  {
    const unsigned short* ps = Pr + (size_t)tid * 32;
#pragma unroll
    for (int u = 0; u < 4; ++u) pf[u] = *(const s16x8*)(ps + 8 * u);
  }

  f32x4 acc[4][4];
#pragma unroll
  for (int i = 0; i < 4; ++i)
#pragma unroll
    for (int j = 0; j < 4; ++j)
#pragma unroll
      for (int r = 0; r < 4; ++r) acc[i][j][r] = 0.f;

  for (int ch = 0; ch < 4; ++ch) {
    __syncthreads();  // ch0: phase-1 reads + q_s writes done; else: P_s readers done
    {
      unsigned short* dst = &P_s[tid * 40];
#pragma unroll
      for (int u = 0; u < 4; ++u) *(s16x8*)(dst + 8 * u) = pf[u];
    }
    __syncthreads();
    if (ch < 3) {  // prefetch next chunk under this chunk's MFMAs
      const unsigned short* ps = Pr + (size_t)((ch + 1) * NPROTO + tid) * 32;
#pragma unroll
      for (int u = 0; u < 4; ++u) pf[u] = *(const s16x8*)(ps + 8 * u);
    }
    const int dk = 32 * ch;
    s16x8 afr[4];
#pragma unroll
    for (int i = 0; i < 4; ++i)
      afr[i] = *(const s16x8*)&q_s[(16 * i + l15) * 136 + dk + 8 * l4];
#pragma unroll
    for (int j = 0; j < 4; ++j) {
      s16x8 bfr = *(const s16x8*)&P_s[(64 * wave + 16 * j + l15) * 40 + 8 * l4];
#pragma unroll
      for (int i = 0; i < 4; ++i)
        acc[i][j] = __builtin_amdgcn_mfma_f32_16x16x32_bf16(afr[i], bfr, acc[i][j], 0, 0, 0);
    }
  }

  // softmax over 512 protos (exp2 domain; qn2 row-constant cancels)
  const float g2  = fabsf(gptr[0]) * 1.44269504088896340736f;
  const float tg2 = 2.f * g2;
  float cj[4];
#pragma unroll
  for (int j = 0; j < 4; ++j) cj[j] = g2 * pn2[64 * wave + 16 * j + l15];

#pragma unroll
  for (int i = 0; i < 4; ++i)
#pragma unroll
    for (int r = 0; r < 4; ++r) {
      float m = -1e30f;
#pragma unroll
      for (int j = 0; j < 4; ++j) {
        float lv = fmaf(acc[i][j][r], tg2, -cj[j]);
        acc[i][j][r] = lv;
        m = fmaxf(m, lv);
      }
#pragma unroll
      for (int s = 1; s < 16; s <<= 1) m = fmaxf(m, __shfl_xor(m, s));
      if (l15 == 0) red[wave * 64 + 16 * i + 4 * l4 + r] = m;
    }
  __syncthreads();
  if (tid < 64) {
    float M = red[tid];
#pragma unroll
    for (int w = 1; w < 8; ++w) M = fmaxf(M, red[w * 64 + tid]);
    rmx[tid] = M;
  }
  __syncthreads();

#pragma unroll
  for (int i = 0; i < 4; ++i) {
    const f32x4 Mi = *(const f32x4*)&rmx[16 * i + 4 * l4];
#pragma unroll
    for (int r = 0; r < 4; ++r) {
      float s = 0.f;
#pragma unroll
      for (int j = 0; j < 4; ++j) {
        float e = exp2f(acc[i][j][r] - Mi[r]);
        acc[i][j][r] = e;
        s += e;
      }
#pragma unroll
      for (int t = 1; t < 16; t <<= 1) s += __shfl_xor(s, t);
      if (l15 == 0) red[wave * 64 + 16 * i + 4 * l4 + r] = s;
    }
  }
  __syncthreads();
  if (tid < 64) {
    float S = 0.f;
#pragma unroll
    for (int w = 0; w < 8; ++w) S += red[w * 64 + tid];
    rinv[tid] = 1.f / S;
  }
  __syncthreads();

  // direct stores: f32x4 over r = 4 consecutive px
  float* ob = out + (size_t)nimg * NPROTO * HW + hw0;
#pragma unroll
  for (int i = 0; i < 4; ++i) {
    const f32x4 iv = *(const f32x4*)&rinv[16 * i + 4 * l4];
    const int px = 16 * i + 4 * l4;
#pragma unroll
    for (int j = 0; j < 4; ++j) {
      const int k = 64 * wave + 16 * j + l15;
      f32x4 o = acc[i][j] * iv;
      *(f32x4*)(ob + (size_t)k * HW + px) = o;
    }
  }
}

extern "C" void kernel_launch(void* const* d_in, const int* in_sizes, int n_in,
                              void* d_out, int out_size, void* d_ws, size_t ws_size,
                              hipStream_t stream) {
  const float* x     = (const float*)d_in[0];
  const float* Wm    = (const float*)d_in[1];
  const float* bias  = (const float*)d_in[2];
  const float* prot  = (const float*)d_in[3];
  const float* gamma = (const float*)d_in[4];
  float* out = (float*)d_out;

  // workspace: Pr chunked bf16 (128 KiB) | pn2 (2 KiB) | W bf16 (64 KiB)
  unsigned short* Pr_w  = (unsigned short*)d_ws;
  float*          pn2_w = (float*)((char*)d_ws + 131072);
  unsigned short* W_ws  = (unsigned short*)((char*)d_ws + 131072 + 2048);

  prep_kernel<<<16, 256, 0, stream>>>(prot, Wm, Pr_w, W_ws, pn2_w);
  fused_kernel<<<1024, 512, 0, stream>>>(x, W_ws, bias, Pr_w, pn2_w, gamma, out);
}

// Round 4
// 213.789 us; speedup vs baseline: 1.1737x; 1.0079x over previous
//
#include <hip/hip_runtime.h>

#define HW 4096
#define NCH 256
#define DIM 128
#define NPROTO 512

typedef __attribute__((ext_vector_type(4))) float f32x4;
typedef __attribute__((ext_vector_type(8))) short s16x8;

__device__ __forceinline__ unsigned short f2bf(float f) {
  union { float f; unsigned u; } v; v.f = f;
  unsigned r = v.u + 0x7fffu + ((v.u >> 16) & 1u);
  return (unsigned short)(r >> 16);
}

// async global->LDS, 16B/lane; LDS dest = wave-uniform base + lane*16
__device__ __forceinline__ void gload_lds16(const void* g, void* l) {
  __builtin_amdgcn_global_load_lds(
      (const __attribute__((address_space(1))) void*)g,
      (__attribute__((address_space(3))) void*)l, 16, 0, 0);
}

// ---------------------------------------------------------------------------
// prep: P -> bf16 chunked Pr[ch][512][32] (+pn2); W -> bf16 row-major [128][256]
// ---------------------------------------------------------------------------
__global__ __launch_bounds__(256) void prep_kernel(const float* __restrict__ P,
                                                   const float* __restrict__ Wm,
                                                   unsigned short* __restrict__ Pr,
                                                   unsigned short* __restrict__ Wbf,
                                                   float* __restrict__ pn2) {
  const int tid = threadIdx.x;
  const int b = blockIdx.x;
  if (b < 8) {
    const int n  = b * 64 + (tid >> 2);
    const int qt = tid & 3;  // d-chunk 32*qt..
    const float* row = P + n * DIM + qt * 32;
    unsigned short* dst = Pr + ((size_t)qt * NPROTO + n) * 32;
    float ssq = 0.f;
#pragma unroll
    for (int u = 0; u < 8; ++u) {
      f32x4 v = *(const f32x4*)(row + 4 * u);
      ssq += v.x * v.x + v.y * v.y + v.z * v.z + v.w * v.w;
      dst[4 * u + 0] = f2bf(v.x);
      dst[4 * u + 1] = f2bf(v.y);
      dst[4 * u + 2] = f2bf(v.z);
      dst[4 * u + 3] = f2bf(v.w);
    }
    ssq += __shfl_xor(ssq, 1);
    ssq += __shfl_xor(ssq, 2);
    if (qt == 0) pn2[n] = ssq;
  } else {
    const int idx = ((b - 8) * 256 + tid) * 16;  // 8*256*16 = 32768 = 128*256
#pragma unroll
    for (int u = 0; u < 4; ++u) {
      f32x4 v = *(const f32x4*)(Wm + idx + 4 * u);
      unsigned short* d = Wbf + idx + 4 * u;
      d[0] = f2bf(v.x); d[1] = f2bf(v.y); d[2] = f2bf(v.z); d[3] = f2bf(v.w);
    }
  }
}

// ---------------------------------------------------------------------------
// fused: 64 px x 512 protos per block, 512 thr (8 waves), 1024 blocks.
// Phase 1 (pipelined, T3/T4-min): dbuf x_b/w_s; per K-step issue next tile's
//   W gload_lds + x loads, pack current x, raw s_barrier with COUNTED
//   vmcnt(4) (next loads stay in flight), MFMA, raw barrier (lgkm only).
// Phase 1.5: q + bias -> bf16 q_s [64 rows x 256B], 16B-unit XOR swizzle
//   keyed (px&7) — same involution on write and read.
// Phase 2 (barrier-free): P is wave-local (wave w protos 64w..64w+63) —
//   staged via gload_lds into per-wave 4KB slab, chunk ch+1 issued under
//   chunk ch MFMAs, vmcnt(0) intra-wave only. Zero __syncthreads in loop.
// Softmax (exp2 domain) + direct f32x4 stores unchanged (proven).
// LDS: q_s 16384 | {x_b 2x9216 + w_s 2x16384 = 51200} overlay P_w 32768 |
//      red 2560 = 70144 B -> 2 blocks/CU (140288 <= 160K).
// ---------------------------------------------------------------------------
__global__ __launch_bounds__(512, 4) void fused_kernel(
    const float* __restrict__ x, const unsigned short* __restrict__ Wbf,
    const float* __restrict__ bias, const unsigned short* __restrict__ Pr,
    const float* __restrict__ pn2, const float* __restrict__ gptr,
    float* __restrict__ out) {
  __shared__ __align__(16) char smem[70144];
  unsigned short* q_s = (unsigned short*)smem;  // [64][128] swizzled (16384 B)
  char* x_b = smem + 16384;                     // dbuf: 2 x (64 rows x 144B)
  char* wsb = smem + 16384 + 18432;             // dbuf: 2 x [128][64] shorts
  char* P_w = smem + 16384;                     // overlay: 8 waves x 4096 B
  float* red  = (float*)(smem + 67584);         // [8][64]
  float* rmx  = (float*)(smem + 69632);         // [64]
  float* rinv = (float*)(smem + 69888);         // [64]

  const int tid  = threadIdx.x;
  const int p0   = blockIdx.x * 64;
  const int nimg = p0 >> 12;
  const int hw0  = p0 & 4095;
  const int wave = tid >> 6, lane = tid & 63;
  const int l15 = lane & 15, l4 = lane >> 4;
  const int wr = wave >> 2, wc = wave & 3;  // phase-1 tile: px 32wr+, d 32wc+

  // ---------------- phase 1: q = x W^T (pipelined) ----------------
  f32x4 acc1[2][2];
#pragma unroll
  for (int i = 0; i < 2; ++i)
#pragma unroll
    for (int j = 0; j < 2; ++j)
#pragma unroll
      for (int r = 0; r < 4; ++r) acc1[i][j][r] = 0.f;

  const float* xb = x + (size_t)nimg * NCH * HW + hw0;
  const int f  = tid & 15;                  // px quad: pixels 4f..4f+3
  const int cp = tid >> 4;                  // channel pair 2cp,2cp+1
  const int wrow = 8 * wave + (lane >> 3);  // W staging row base
  const int wu   = lane & 7;                // 16B unit in 128B row

  // prologue: W(0) -> w_s[0], x(0) -> regs
#pragma unroll
  for (int t = 0; t < 2; ++t) {
    const int row = 64 * t + wrow;
    gload_lds16(Wbf + (size_t)row * NCH + ((wu ^ (row & 7)) << 3),
                wsb + t * 8192 + wave * 1024);
  }
  f32x4 cv0 = *(const f32x4*)(xb + (size_t)(2 * cp + 0) * HW + 4 * f);
  f32x4 cv1 = *(const f32x4*)(xb + (size_t)(2 * cp + 1) * HW + 4 * f);

#pragma unroll
  for (int it = 0; it < 4; ++it) {
    const int buf = it & 1;
    const int c0n = 64 * (it + 1);
    if (it < 3) {  // next W tile -> other buffer (in flight across barriers)
#pragma unroll
      for (int t = 0; t < 2; ++t) {
        const int row = 64 * t + wrow;
        gload_lds16(Wbf + (size_t)row * NCH + c0n + ((wu ^ (row & 7)) << 3),
                    wsb + (buf ^ 1) * 16384 + t * 8192 + wave * 1024);
      }
    }
    f32x4 nv0 = cv0, nv1 = cv1;
    if (it < 3) {  // next x tile -> regs (in flight across barriers)
      nv0 = *(const f32x4*)(xb + (size_t)(c0n + 2 * cp + 0) * HW + 4 * f);
      nv1 = *(const f32x4*)(xb + (size_t)(c0n + 2 * cp + 1) * HW + 4 * f);
    }
    // pack current x -> x_b[buf] (compiler waits the cv regs = retires W(it))
#pragma unroll
    for (int s = 0; s < 4; ++s) {
      const int row = 4 * f + s;
      unsigned pk = (unsigned)f2bf(cv0[s]) | ((unsigned)f2bf(cv1[s]) << 16);
      *(unsigned*)(x_b + buf * 9216 + row * 144 +
                   ((4 * cp) ^ (((row >> 2) & 7) << 4))) = pk;
    }
    // counted wait: keep this iter's 4 new VMEM ops in flight; drain older
    if (it < 3) asm volatile("s_waitcnt vmcnt(4) lgkmcnt(0)" ::: "memory");
    else        asm volatile("s_waitcnt vmcnt(0) lgkmcnt(0)" ::: "memory");
    __builtin_amdgcn_s_barrier();
#pragma unroll
    for (int kc = 0; kc < 64; kc += 32) {
      const int ub = (kc >> 3) + l4;  // 16B unit 0..7
      s16x8 a[2];
#pragma unroll
      for (int i = 0; i < 2; ++i) {
        const int row = 32 * wr + 16 * i + l15;
        a[i] = *(const s16x8*)(x_b + buf * 9216 + row * 144 +
                               16 * (ub ^ ((row >> 2) & 7)));
      }
#pragma unroll
      for (int j = 0; j < 2; ++j) {
        s16x8 b = *(const s16x8*)(wsb + buf * 16384 +
                                  (32 * wc + 16 * j + l15) * 128 +
                                  ((ub ^ (l15 & 7)) << 4));
#pragma unroll
        for (int i = 0; i < 2; ++i)
          acc1[i][j] = __builtin_amdgcn_mfma_f32_16x16x32_bf16(a[i], b, acc1[i][j], 0, 0, 0);
      }
    }
    // readers-done barrier: lgkm only, vmcnt stays in flight
    asm volatile("s_waitcnt lgkmcnt(0)" ::: "memory");
    __builtin_amdgcn_s_barrier();
    cv0 = nv0; cv1 = nv1;
  }

  // issue P chunk 0 now (overlay region free: all phase-1 readers done)
#pragma unroll
  for (int t = 0; t < 4; ++t)
    gload_lds16(Pr + (size_t)(64 * wave + 16 * t) * 32 + 8 * lane,
                P_w + wave * 4096 + t * 1024);

  // ---------------- phase 1.5: q + bias -> q_s (swizzled bf16) ----------------
  // C/D layout: col = l15 (d within 16-tile), row = 4*l4 + r (px)
#pragma unroll
  for (int j = 0; j < 2; ++j) {
    const int d = 32 * wc + 16 * j + l15;
    const float bv = bias[d];
    const int u  = d >> 3;
    const int d7 = d & 7;
#pragma unroll
    for (int i = 0; i < 2; ++i) {
      const int pxb = 32 * wr + 16 * i + 4 * l4;
#pragma unroll
      for (int r = 0; r < 4; ++r) {
        const int px = pxb + r;
        q_s[px * 128 + ((u ^ (px & 7)) << 3) + d7] = f2bf(acc1[i][j][r] + bv);
      }
    }
  }
  __syncthreads();  // q_s visible to all waves; drains P chunk-0 gloads

  // ---------------- phase 2: attn (barrier-free chunk loop) ----------------
  f32x4 acc[4][4];
#pragma unroll
  for (int i = 0; i < 4; ++i)
#pragma unroll
    for (int j = 0; j < 4; ++j)
#pragma unroll
      for (int r = 0; r < 4; ++r) acc[i][j][r] = 0.f;

  const unsigned short* Pw = (const unsigned short*)(P_w + wave * 4096);

#pragma unroll
  for (int ch = 0; ch < 4; ++ch) {
    if (ch) asm volatile("s_waitcnt vmcnt(0)" ::: "memory");  // P chunk landed
    s16x8 afr[4];
#pragma unroll
    for (int i = 0; i < 4; ++i) {
      const int px = 16 * i + l15;
      afr[i] = *(const s16x8*)&q_s[px * 128 + (((4 * ch + l4) ^ (l15 & 7)) << 3)];
    }
#pragma unroll
    for (int j = 0; j < 4; ++j) {
      s16x8 bfr = *(const s16x8*)&Pw[(16 * j + l15) * 32 + 8 * l4];
#pragma unroll
      for (int i = 0; i < 4; ++i)
        acc[i][j] = __builtin_amdgcn_mfma_f32_16x16x32_bf16(afr[i], bfr, acc[i][j], 0, 0, 0);
    }
    if (ch < 3) {  // next chunk under nothing-left-to-read (wave-local slab)
      __builtin_amdgcn_sched_barrier(0);
#pragma unroll
      for (int t = 0; t < 4; ++t)
        gload_lds16(Pr + (size_t)((ch + 1) * NPROTO + 64 * wave + 16 * t) * 32 + 8 * lane,
                    P_w + wave * 4096 + t * 1024);
    }
  }

  // softmax over 512 protos (exp2 domain; qn2 row-constant cancels)
  const float g2  = fabsf(gptr[0]) * 1.44269504088896340736f;
  const float tg2 = 2.f * g2;
  float cj[4];
#pragma unroll
  for (int j = 0; j < 4; ++j) cj[j] = g2 * pn2[64 * wave + 16 * j + l15];

#pragma unroll
  for (int i = 0; i < 4; ++i)
#pragma unroll
    for (int r = 0; r < 4; ++r) {
      float m = -1e30f;
#pragma unroll
      for (int j = 0; j < 4; ++j) {
        float lv = fmaf(acc[i][j][r], tg2, -cj[j]);
        acc[i][j][r] = lv;
        m = fmaxf(m, lv);
      }
#pragma unroll
      for (int s = 1; s < 16; s <<= 1) m = fmaxf(m, __shfl_xor(m, s));
      if (l15 == 0) red[wave * 64 + 16 * i + 4 * l4 + r] = m;
    }
  __syncthreads();
  if (tid < 64) {
    float M = red[tid];
#pragma unroll
    for (int w = 1; w < 8; ++w) M = fmaxf(M, red[w * 64 + tid]);
    rmx[tid] = M;
  }
  __syncthreads();

#pragma unroll
  for (int i = 0; i < 4; ++i) {
    const f32x4 Mi = *(const f32x4*)&rmx[16 * i + 4 * l4];
#pragma unroll
    for (int r = 0; r < 4; ++r) {
      float s = 0.f;
#pragma unroll
      for (int j = 0; j < 4; ++j) {
        float e = exp2f(acc[i][j][r] - Mi[r]);
        acc[i][j][r] = e;
        s += e;
      }
#pragma unroll
      for (int t = 1; t < 16; t <<= 1) s += __shfl_xor(s, t);
      if (l15 == 0) red[wave * 64 + 16 * i + 4 * l4 + r] = s;
    }
  }
  __syncthreads();
  if (tid < 64) {
    float S = 0.f;
#pragma unroll
    for (int w = 0; w < 8; ++w) S += red[w * 64 + tid];
    rinv[tid] = 1.f / S;
  }
  __syncthreads();

  // direct stores: f32x4 over r = 4 consecutive px
  float* ob = out + (size_t)nimg * NPROTO * HW + hw0;
#pragma unroll
  for (int i = 0; i < 4; ++i) {
    const f32x4 iv = *(const f32x4*)&rinv[16 * i + 4 * l4];
    const int px = 16 * i + 4 * l4;
#pragma unroll
    for (int j = 0; j < 4; ++j) {
      const int k = 64 * wave + 16 * j + l15;
      f32x4 o = acc[i][j] * iv;
      *(f32x4*)(ob + (size_t)k * HW + px) = o;
    }
  }
}

extern "C" void kernel_launch(void* const* d_in, const int* in_sizes, int n_in,
                              void* d_out, int out_size, void* d_ws, size_t ws_size,
                              hipStream_t stream) {
  const float* x     = (const float*)d_in[0];
  const float* Wm    = (const float*)d_in[1];
  const float* bias  = (const float*)d_in[2];
  const float* prot  = (const float*)d_in[3];
  const float* gamma = (const float*)d_in[4];
  float* out = (float*)d_out;

  // workspace: Pr chunked bf16 (128 KiB) | pn2 (2 KiB) | W bf16 (64 KiB)
  unsigned short* Pr_w  = (unsigned short*)d_ws;
  float*          pn2_w = (float*)((char*)d_ws + 131072);
  unsigned short* W_ws  = (unsigned short*)((char*)d_ws + 131072 + 2048);

  prep_kernel<<<16, 256, 0, stream>>>(prot, Wm, Pr_w, W_ws, pn2_w);
  fused_kernel<<<1024, 512, 0, stream>>>(x, W_ws, bias, Pr_w, pn2_w, gamma, out);
}